// Round 5
// baseline (527.401 us; speedup 1.0000x reference)
//
#include <hip/hip_runtime.h>

// Shapes from the reference:
//   action [B=128, A=256] f32, conv_w [E=256, A=256] f32, conv_b [E=256] f32
//   out [B=128, E=256, H=64, W=64] f32  (512 MiB -> store-BW bound, ~85us floor)
#define B_DIM 128
#define A_DIM 256
#define E_DIM 256
#define HW    4096   // 64*64
#define CHUNKS_PER_BLOCK 16

// Native vector type — __builtin_nontemporal_store rejects HIP_vector_type.
typedef float f32x4 __attribute__((ext_vector_type(4)));

// Kernel 1: y[b,e] = relu(dot(action[b,:], conv_w[e,:]) + conv_b[e])
// One block per b (128 blocks), one thread per e (256 threads). ~4us total.
__global__ void __launch_bounds__(256) compute_y_kernel(
    const float* __restrict__ action,
    const float* __restrict__ conv_w,
    const float* __restrict__ conv_b,
    float* __restrict__ y)
{
    const int b = blockIdx.x;
    const int e = threadIdx.x;

    __shared__ float act[A_DIM];
    act[e] = action[b * A_DIM + e];   // blockDim.x == A_DIM == 256
    __syncthreads();

    const float4* w4 = reinterpret_cast<const float4*>(conv_w + e * A_DIM);
    const float4* a4 = reinterpret_cast<const float4*>(act);

    float sum = conv_b[e];
    #pragma unroll
    for (int i = 0; i < A_DIM / 4; ++i) {
        float4 w = w4[i];
        float4 a = a4[i];
        sum = fmaf(a.x, w.x, sum);
        sum = fmaf(a.y, w.y, sum);
        sum = fmaf(a.z, w.z, sum);
        sum = fmaf(a.w, w.w, sum);
    }
    y[b * E_DIM + e] = fmaxf(sum, 0.0f);
}

// Kernel 2: fill-clone broadcast. 2048 blocks x 256 threads (8 blocks/CU).
// Each block owns 16 chunks = 256 KB of contiguous output. The 16 y-values
// are preloaded before any store (uniform addresses -> scalarized), then
// each thread issues 64 independent non-temporal dwordx4 stores with affine
// addresses — deep store queue, no loads inside the store stream. This is
// structurally the rocclr fill that measures 6.3 TB/s.
__global__ void __launch_bounds__(256) broadcast_y_kernel(
    const float* __restrict__ y,
    f32x4* __restrict__ out)
{
    const int c0 = blockIdx.x * CHUNKS_PER_BLOCK;

    float v[CHUNKS_PER_BLOCK];
    #pragma unroll
    for (int j = 0; j < CHUNKS_PER_BLOCK; ++j)
        v[j] = y[c0 + j];            // uniform per block -> s_load

    f32x4* dst = out + (size_t)c0 * (HW / 4) + threadIdx.x;
    #pragma unroll
    for (int j = 0; j < CHUNKS_PER_BLOCK; ++j) {
        const float s = v[j];
        const f32x4 v4 = {s, s, s, s};
        #pragma unroll
        for (int k = 0; k < 4; ++k)
            __builtin_nontemporal_store(v4, dst + j * (HW / 4) + k * 256);
    }
}

extern "C" void kernel_launch(void* const* d_in, const int* in_sizes, int n_in,
                              void* d_out, int out_size, void* d_ws, size_t ws_size,
                              hipStream_t stream) {
    const float* action = (const float*)d_in[0];
    const float* conv_w = (const float*)d_in[1];
    const float* conv_b = (const float*)d_in[2];
    float* out = (float*)d_out;
    float* y   = (float*)d_ws;   // needs B*E*4 = 128 KiB scratch

    compute_y_kernel<<<B_DIM, 256, 0, stream>>>(action, conv_w, conv_b, y);

    broadcast_y_kernel<<<(B_DIM * E_DIM) / CHUNKS_PER_BLOCK, 256, 0, stream>>>(
        y, reinterpret_cast<f32x4*>(out));
}